// Round 23
// baseline (593.387 us; speedup 1.0000x reference)
//
#include <hip/hip_runtime.h>
#include <hip/hip_fp16.h>
#include <cstdint>
#include <cstddef>

#define BB 128
#define NN 1024
#define NI 64
#define TT 512
#define MAXNNZ 16384
#define NE 28
#define TH 16

// ws layout (bytes)
#define WS_OFFS   0u         // int[1025]
#define WS_IDX    16384u     // u16[MAXNNZ]
#define WS_VAL    65536u     // f32[MAXNNZ]
#define WS_PERM   131072u    // int[1024]
#define WS_IPERM  135168u    // int[1024]
#define WS_XSTATE 139264u    // f32[BB*NN] (fallback only)
#define WS_WINP   663552u    // f32[NI*NN]
#define WS_EIDX2  925696u    // u16[NE*NN] = 57344
#define WS_CNT16  983040u    // int[1024*16]
#define WS_OFF16  1048576u   // int[1024*16]
#define WS_U      1114112u   // fp16 U buffer 0 [<=256][BB][NN] = 67108864
#define WS_U2     (WS_U + 67108864u) // fp16 U buffer 1

// ---------- sparse build (parallel, deterministic k-order) ----------
__global__ __launch_bounds__(64) void k_count16(const float* __restrict__ W, int* __restrict__ cnt16) {
    int bc = blockIdx.x;
    int s = bc & 15, g = bc >> 4;
    int col = g * 64 + threadIdx.x;
    int c = 0;
    for (int q = 0; q < 64; ++q) {
        int k = s * 64 + q;
        c += (W[(size_t)k * NN + col] != 0.0f) ? 1 : 0;
    }
    cnt16[col * 16 + s] = c;
}

// fused: scan (offs, off16) + rank (count-sort) + permuted Winp
__global__ __launch_bounds__(1024) void k_scanrank(const int* __restrict__ cnt16,
        int* __restrict__ offs, int* __restrict__ off16,
        int* __restrict__ perm, int* __restrict__ iperm,
        const float* __restrict__ Win, float* __restrict__ Winp) {
    __shared__ int s[NN];
    __shared__ int sperm[NN];
    int n = threadIdx.x;
    int t = 0;
#pragma unroll
    for (int q = 0; q < 16; ++q) t += cnt16[n * 16 + q];
    s[n] = t;
    __syncthreads();
    for (int d = 1; d < NN; d <<= 1) {
        int v = (n >= d) ? s[n - d] : 0;
        __syncthreads();
        s[n] += v;
        __syncthreads();
    }
    int incl = s[n];
    offs[n + 1] = (incl < MAXNNZ) ? incl : MAXNNZ;
    if (n == 0) offs[0] = 0;
    int base = incl - t;
#pragma unroll
    for (int q = 0; q < 16; ++q) {
        off16[n * 16 + q] = base;
        base += cnt16[n * 16 + q];
    }
    __syncthreads();
    int myc = t;
    s[n] = myc;
    __syncthreads();
    int r = 0;
    for (int m = 0; m < NN; ++m) {
        int cm = s[m];
        r += (cm > myc || (cm == myc && m < n)) ? 1 : 0;
    }
    perm[r] = n;
    iperm[n] = r;
    sperm[r] = n;
    __syncthreads();
    // Winp[i][r] = Win[i][perm[r]]
    int pc = sperm[n];
    for (int i = 0; i < NI; ++i)
        Winp[(i << 10) + n] = Win[(i << 10) + pc];
}

__global__ __launch_bounds__(64) void k_fill16(const float* __restrict__ W, const int* __restrict__ off16,
                                               unsigned short* __restrict__ idx, float* __restrict__ val) {
    int bc = blockIdx.x;
    int s = bc & 15, g = bc >> 4;
    int col = g * 64 + threadIdx.x;
    int p = off16[col * 16 + s];
    for (int q = 0; q < 64; ++q) {
        int k = s * 64 + q;
        float w = W[(size_t)k * NN + col];
        if (w != 0.0f) { idx[p] = (unsigned short)k; val[p] = w; ++p; }
    }
}

// cohort-aware 2-choice bank assignment (needs idx from fill16)
__global__ __launch_bounds__(1024) void k_choice2(const int* __restrict__ offs,
        const unsigned short* __restrict__ gidx, const int* __restrict__ perm,
        const int* __restrict__ iperm, unsigned short* __restrict__ eidx2) {
    __shared__ unsigned short rk[NN][NE];
    __shared__ unsigned short scnt[NN];
    __shared__ unsigned char ctr8[896][32];
    int n = threadIdx.x;
    {
        int rr = n;
        int c = perm[rr];
        int o0 = offs[c];
        int cn = offs[c + 1] - o0;
        if (cn > NE) cn = NE;
        scnt[rr] = (unsigned short)cn;
        for (int j = 0; j < cn; ++j) rk[rr][j] = (unsigned short)iperm[(int)gidx[o0 + j]];
    }
    __syncthreads();
    int tid = n;
    if (tid < 896) {
        int task = tid >> 1, h = tid & 1;
        int w = task / NE, j = task % NE;
        unsigned char* mc = &ctr8[tid][0];
        for (int b = 0; b < 32; ++b) mc[b] = 0;
        unsigned sel = 0u;
        for (int l = 0; l < 32; ++l) {
            int rr = 64 * w + 32 * h + l;
            if (j < (int)scnt[rr]) {
                int rv = (int)rk[rr][j];
                int bA = rv & 31, bB = (rv ^ (rv >> 5)) & 31;
                if (mc[bA] <= mc[bB]) mc[bA]++;
                else { sel |= (1u << l); mc[bB]++; }
            }
        }
        for (int sweep = 0; sweep < 12; ++sweep) {
            bool ch = false;
            for (int l = 0; l < 32; ++l) {
                int rr = 64 * w + 32 * h + l;
                if (j < (int)scnt[rr]) {
                    int rv = (int)rk[rr][j];
                    int bA = rv & 31, bB = (rv ^ (rv >> 5)) & 31;
                    int isB = (int)((sel >> l) & 1u);
                    int cur = isB ? bB : bA, alt = isB ? bA : bB;
                    if ((int)mc[cur] > (int)mc[alt] + 1) {
                        mc[cur]--; mc[alt]++;
                        sel ^= (1u << l);
                        ch = true;
                    }
                }
            }
            if (!ch) break;
        }
        for (int l = 0; l < 32; ++l) {
            int rr = 64 * w + 32 * h + l;
            if (j < (int)scnt[rr]) {
                int rv = (int)rk[rr][j];
                int bB = (rv ^ (rv >> 5)) & 31;
                int addr = ((sel >> l) & 1u) ? (4096 + (((rv & ~31) | bB) << 2))
                                             : (rv << 2);
                eidx2[j * NN + rr] = (unsigned short)addr;
            }
        }
        int minb = 0, minl = (int)mc[0];
        for (int b = 1; b < 32; ++b)
            if ((int)mc[b] < minl) { minl = (int)mc[b]; minb = b; }
        unsigned short pad = (unsigned short)(minb << 2);
        for (int l = 0; l < 32; ++l) {
            int rr = 64 * w + 32 * h + l;
            if (j >= (int)scnt[rr]) eidx2[j * NN + rr] = pad;
        }
    }
}

// ---------- standalone input projection (prime chunk): U[t][b][r] fp16 ----------
__global__ __launch_bounds__(256) void k_uproj3(const float* __restrict__ In, const float* __restrict__ Winp,
                                                __half* __restrict__ U, int t0c, int nblk) {
    int b  = blockIdx.x / nblk;
    int tq = blockIdx.x % nblk;
    int t0 = t0c + tq * 32;
    __shared__ float s[32][NI + 1];
    int tid = threadIdx.x;
    {
        int i = tid >> 2, g = tid & 3;
        const float* ip = In + ((size_t)b * NI + i) * TT + t0 + g * 8;
        float4 v0 = *(const float4*)(ip);
        float4 v1 = *(const float4*)(ip + 4);
        s[g * 8 + 0][i] = v0.x; s[g * 8 + 1][i] = v0.y;
        s[g * 8 + 2][i] = v0.z; s[g * 8 + 3][i] = v0.w;
        s[g * 8 + 4][i] = v1.x; s[g * 8 + 5][i] = v1.y;
        s[g * 8 + 6][i] = v1.z; s[g * 8 + 7][i] = v1.w;
    }
    __syncthreads();
    const float4* W4 = (const float4*)Winp;
    uint2* U2 = (uint2*)U;
    for (int th = 0; th < 2; ++th) {
        float4 acc[16];
#pragma unroll
        for (int t = 0; t < 16; ++t) acc[t] = make_float4(0.f, 0.f, 0.f, 0.f);
        for (int i = 0; i < NI; ++i) {
            float4 w = W4[(size_t)i * 256 + tid];
#pragma unroll
            for (int t = 0; t < 16; ++t) {
                float sv = s[th * 16 + t][i];
                acc[t].x = fmaf(w.x, sv, acc[t].x);
                acc[t].y = fmaf(w.y, sv, acc[t].y);
                acc[t].z = fmaf(w.z, sv, acc[t].z);
                acc[t].w = fmaf(w.w, sv, acc[t].w);
            }
        }
#pragma unroll
        for (int t = 0; t < 16; ++t) {
            __half2 h01 = __floats2half2_rn(acc[t].x, acc[t].y);
            __half2 h23 = __floats2half2_rn(acc[t].z, acc[t].w);
            uint2 pk;
            pk.x = *(unsigned int*)&h01;
            pk.y = *(unsigned int*)&h23;
            U2[((size_t)(tq * 32 + th * 16 + t) * BB + b) * 256 + tid] = pk;
        }
    }
}

// ---------- recurrence helpers ----------
__device__ __forceinline__ float fast_tanh(float z) {
    float a = fabsf(z) * 2.885390082f;       // 2*log2(e)
    a = fminf(a, 60.0f);
    float e = __builtin_amdgcn_exp2f(a);     // e^{2|z|}
    float r = 1.0f - __fdividef(2.0f, e + 1.0f);
    return z < 0.0f ? -r : r;
}

#define L28(M) \
  M(0) M(1) M(2) M(3) M(4) M(5) M(6) M(7) M(8) M(9) M(10) M(11) M(12) M(13) \
  M(14) M(15) M(16) M(17) M(18) M(19) M(20) M(21) M(22) M(23) M(24) M(25) M(26) M(27)

#define DW(i)  float w##i; int a##i;
#define IW(i)  { a##i = (int)eidx2[(i) * NN + n]; \
                 w##i = (cnt > i) ? gval[o0 + i] : 0.0f; }

#define PIN_ALL \
  asm volatile("" : "+v"(w0),"+v"(w1),"+v"(w2),"+v"(w3),"+v"(w4),"+v"(w5),"+v"(w6),"+v"(w7)); \
  asm volatile("" : "+v"(w8),"+v"(w9),"+v"(w10),"+v"(w11),"+v"(w12),"+v"(w13),"+v"(w14),"+v"(w15)); \
  asm volatile("" : "+v"(w16),"+v"(w17),"+v"(w18),"+v"(w19),"+v"(w20),"+v"(w21),"+v"(w22),"+v"(w23)); \
  asm volatile("" : "+v"(w24),"+v"(w25),"+v"(w26),"+v"(w27)); \
  asm volatile("" : "+v"(a0),"+v"(a1),"+v"(a2),"+v"(a3),"+v"(a4),"+v"(a5),"+v"(a6),"+v"(a7)); \
  asm volatile("" : "+v"(a8),"+v"(a9),"+v"(a10),"+v"(a11),"+v"(a12),"+v"(a13),"+v"(a14),"+v"(a15)); \
  asm volatile("" : "+v"(a16),"+v"(a17),"+v"(a18),"+v"(a19),"+v"(a20),"+v"(a21),"+v"(a22),"+v"(a23)); \
  asm volatile("" : "+v"(a24),"+v"(a25),"+v"(a26),"+v"(a27));

#define GRP(J, i0, i1, i2, i3) \
  if ((J) < wmax) { \
    float q0 = *(const float*)(xp + a##i0); \
    float q1 = *(const float*)(xp + a##i1); \
    float q2 = *(const float*)(xp + a##i2); \
    float q3 = *(const float*)(xp + a##i3); \
    z0 = fmaf(w##i0, q0, z0); z1 = fmaf(w##i1, q1, z1); \
    z2 = fmaf(w##i2, q2, z2); z3 = fmaf(w##i3, q3, z3); \
  }

#define GATHER_ALL \
  GRP(0, 0,1,2,3)      GRP(4, 4,5,6,7)      GRP(8, 8,9,10,11) \
  GRP(12, 12,13,14,15) GRP(16, 16,17,18,19) GRP(20, 20,21,22,23) \
  GRP(24, 24,25,26,27)

// prefetch depth 2 with clamp tlim (inclusive max t)
#define STEPX(PH, XDST) { \
    float u = un1; un1 = un2; \
    int tn = t + 2; tn = (tn < tlim) ? tn : tlim; \
    un2 = (float)Ub[(size_t)tn * ustep]; \
    const char* xp = xb + (PH); \
    float z0 = u, z1 = 0.f, z2 = 0.f, z3 = 0.f; \
    GATHER_ALL \
    x = 0.5f * x + 0.5f * fast_tanh((z0 + z1) + (z2 + z3)); \
    XDST = x; \
    float* wb = (float*)(xb + ((PH) ^ 8192)); \
    wb[n] = x; \
    wb[NN + nB] = x; \
    __syncthreads(); \
    ++t; \
}

#define REC16 \
    PIN_ALL \
    int t = tb; \
    float y0, y1, y2, y3, y4, y5, y6, y7, y8, y9, y10, y11, y12, y13, y14, y15; \
    STEPX(0,    y0)  STEPX(8192, y1)  STEPX(0,    y2)  STEPX(8192, y3) \
    STEPX(0,    y4)  STEPX(8192, y5)  STEPX(0,    y6)  STEPX(8192, y7) \
    STEPX(0,    y8)  STEPX(8192, y9)  STEPX(0,    y10) STEPX(8192, y11) \
    STEPX(0,    y12) STEPX(8192, y13) STEPX(0,    y14) STEPX(8192, y15)

// ---------- fused: blocks 0..127 recurrence [t0r,t0r+Tc); 128..255 uproj [t0u,t0u+Tcu) ----------
__global__ __launch_bounds__(1024, 4)
void k_fused(const __half* __restrict__ Uread, __half* __restrict__ Uwrite,
             const float* __restrict__ In, const float* __restrict__ Winp,
             const int* __restrict__ offs, const unsigned short* __restrict__ eidx2,
             const float* __restrict__ gval, const int* __restrict__ perm,
             float* __restrict__ out, float* __restrict__ xstate,
             int t0r, int Tc, int t0u, int Tcu) {
    __shared__ float smem[4 * 32 * 65];      // 33280 B; recurrence uses first 16 KB
    int tid = threadIdx.x;
    if (blockIdx.x < BB) {
        int b = blockIdx.x, n = tid;
        int c = perm[n];
        int nB = (n & ~31) | ((n ^ (n >> 5)) & 31);
        int o0 = offs[c];
        int cnt = offs[c + 1] - o0;
        L28(DW)
        L28(IW)
        PIN_ALL
        int wmax = cnt;
#pragma unroll
        for (int d = 1; d < 64; d <<= 1) {
            int o = __shfl_xor(wmax, d);
            wmax = wmax > o ? wmax : o;
        }
        wmax = __builtin_amdgcn_readfirstlane(wmax);

        float x = (t0r == 0) ? 0.0f : xstate[((size_t)b << 10) + n];
        smem[n] = x;
        smem[NN + nB] = x;
        __syncthreads();

        char* xb = (char*)&smem[0];
        const __half* Ub = Uread + (size_t)b * NN + n;
        const size_t ustep = (size_t)BB * NN;
        int tlim = Tc - 1;
        float un1 = (float)Ub[0];
        float un2 = (float)Ub[(size_t)((1 < Tc) ? 1 : 0) * ustep];

        for (int tb = 0; tb < Tc; tb += TH) {
            REC16
            float4* op = (float4*)(out + ((size_t)b * NN + c) * TT + (size_t)(t0r + tb));
            op[0] = make_float4(y0,  y1,  y2,  y3);
            op[1] = make_float4(y4,  y5,  y6,  y7);
            op[2] = make_float4(y8,  y9,  y10, y11);
            op[3] = make_float4(y12, y13, y14, y15);
        }
        if (t0r + Tc < TT) xstate[((size_t)b << 10) + n] = x;
    } else {
        if (Tcu <= 0) return;
        int b = blockIdx.x - BB;
        int sub = tid >> 8, stid = tid & 255;
        float* sg = smem + sub * 32 * 65;     // [t][i] view: sg[t*65+i]
        const float4* W4 = (const float4*)Winp;
        uint2* U2w = (uint2*)Uwrite;
        int ntile = Tcu >> 5;
        int nrep = (ntile + 3) >> 2;
        for (int rep = 0; rep < nrep; ++rep) {
            int tq = rep * 4 + sub;
            bool act = tq < ntile;
            int tg = t0u + tq * 32;
            __syncthreads();
            if (act) {
                int i = stid >> 2, g4 = stid & 3;
                const float* ip = In + ((size_t)b * NI + i) * TT + tg + g4 * 8;
                float4 v0 = *(const float4*)(ip);
                float4 v1 = *(const float4*)(ip + 4);
                sg[(g4 * 8 + 0) * 65 + i] = v0.x; sg[(g4 * 8 + 1) * 65 + i] = v0.y;
                sg[(g4 * 8 + 2) * 65 + i] = v0.z; sg[(g4 * 8 + 3) * 65 + i] = v0.w;
                sg[(g4 * 8 + 4) * 65 + i] = v1.x; sg[(g4 * 8 + 5) * 65 + i] = v1.y;
                sg[(g4 * 8 + 6) * 65 + i] = v1.z; sg[(g4 * 8 + 7) * 65 + i] = v1.w;
            }
            __syncthreads();
            if (act) {
                for (int th = 0; th < 2; ++th) {
                    float4 acc[16];
#pragma unroll
                    for (int t = 0; t < 16; ++t) acc[t] = make_float4(0.f, 0.f, 0.f, 0.f);
                    for (int i = 0; i < NI; ++i) {
                        float4 w = W4[(size_t)i * 256 + stid];
#pragma unroll
                        for (int t = 0; t < 16; ++t) {
                            float sv = sg[(th * 16 + t) * 65 + i];
                            acc[t].x = fmaf(w.x, sv, acc[t].x);
                            acc[t].y = fmaf(w.y, sv, acc[t].y);
                            acc[t].z = fmaf(w.z, sv, acc[t].z);
                            acc[t].w = fmaf(w.w, sv, acc[t].w);
                        }
                    }
#pragma unroll
                    for (int t = 0; t < 16; ++t) {
                        __half2 h01 = __floats2half2_rn(acc[t].x, acc[t].y);
                        __half2 h23 = __floats2half2_rn(acc[t].z, acc[t].w);
                        uint2 pk;
                        pk.x = *(unsigned int*)&h01;
                        pk.y = *(unsigned int*)&h23;
                        U2w[((size_t)(tq * 32 + th * 16 + t) * BB + b) * 256 + stid] = pk;
                    }
                }
            }
        }
    }
}

extern "C" void kernel_launch(void* const* d_in, const int* in_sizes, int n_in,
                              void* d_out, int out_size, void* d_ws, size_t ws_size,
                              hipStream_t stream) {
    const float* In  = (const float*)d_in[0];
    const float* W   = (const float*)d_in[1];
    const float* Win = (const float*)d_in[2];
    float* out = (float*)d_out;
    char* ws = (char*)d_ws;
    int* offs           = (int*)(ws + WS_OFFS);
    unsigned short* idx = (unsigned short*)(ws + WS_IDX);
    float* val          = (float*)(ws + WS_VAL);
    int* perm           = (int*)(ws + WS_PERM);
    int* iperm          = (int*)(ws + WS_IPERM);
    float* xstate       = (float*)(ws + WS_XSTATE);
    float* Winp         = (float*)(ws + WS_WINP);
    unsigned short* eidx2 = (unsigned short*)(ws + WS_EIDX2);
    int* cnt16          = (int*)(ws + WS_CNT16);
    int* off16          = (int*)(ws + WS_OFF16);
    __half* U0          = (__half*)(ws + WS_U);
    __half* U1          = (__half*)(ws + WS_U2);

    k_count16<<<256, 64, 0, stream>>>(W, cnt16);
    k_scanrank<<<1, 1024, 0, stream>>>(cnt16, offs, off16, perm, iperm, Win, Winp);
    k_fill16<<<256, 64, 0, stream>>>(W, off16, idx, val);
    k_choice2<<<1, 1024, 0, stream>>>(offs, idx, perm, iperm, eidx2);

    if ((size_t)WS_U2 + (size_t)256 * BB * NN * 2 <= ws_size) {
        // tail-maximizing stagger: prime 64 (full GPU), then
        // rec64||up160, rec160||up256, rec256||up32, rec32 (pure tail)
        k_uproj3<<<BB * 2, 256, 0, stream>>>(In, Winp, U0, 0, 2);
        k_fused<<<2 * BB, 1024, 0, stream>>>(U0, U1, In, Winp, offs, eidx2, val, perm,
                                             out, xstate, 0, 64, 64, 160);
        k_fused<<<2 * BB, 1024, 0, stream>>>(U1, U0, In, Winp, offs, eidx2, val, perm,
                                             out, xstate, 64, 160, 224, 256);
        k_fused<<<2 * BB, 1024, 0, stream>>>(U0, U1, In, Winp, offs, eidx2, val, perm,
                                             out, xstate, 224, 256, 480, 32);
        k_fused<<<BB, 1024, 0, stream>>>(U1, U0, In, Winp, offs, eidx2, val, perm,
                                         out, xstate, 480, 32, TT, 0);
    } else {
        // fallback: serial chunks of 128 in U0
        for (int t0 = 0; t0 < TT; t0 += 128) {
            k_uproj3<<<BB * 4, 256, 0, stream>>>(In, Winp, U0, t0, 4);
            k_fused<<<BB, 1024, 0, stream>>>(U0, U0, In, Winp, offs, eidx2, val, perm,
                                             out, xstate, t0, 128, TT, 0);
        }
    }
}

// Round 24
// 557.707 us; speedup vs baseline: 1.0640x; 1.0640x over previous
//
#include <hip/hip_runtime.h>
#include <hip/hip_fp16.h>
#include <cstdint>
#include <cstddef>

#define BB 128
#define NN 1024
#define NI 64
#define TT 512
#define MAXNNZ 16384
#define NE 28
#define TH 16

// ws layout (bytes)
#define WS_OFFS   0u         // int[1025]
#define WS_IDX    16384u     // u16[MAXNNZ]
#define WS_VAL    65536u     // f32[MAXNNZ]
#define WS_PERM   131072u    // int[1024]
#define WS_IPERM  135168u    // int[1024]
#define WS_XSTATE 139264u    // f32[BB*NN] (fallback only)
#define WS_WINP   663552u    // f32[NI*NN]
#define WS_EIDX2  925696u    // u16[NE*NN] = 57344
#define WS_CNT16  983040u    // int[1024*16]
#define WS_OFF16  1048576u   // int[1024*16]
#define WS_U      1114112u   // fp16 U buffer 0 [<=256][BB][NN] = 67108864
#define WS_U2     (WS_U + 67108864u) // fp16 U buffer 1

// ---------- sparse build (parallel, deterministic k-order) ----------
__global__ __launch_bounds__(64) void k_count16(const float* __restrict__ W, int* __restrict__ cnt16) {
    int bc = blockIdx.x;
    int s = bc & 15, g = bc >> 4;
    int col = g * 64 + threadIdx.x;
    int c = 0;
    for (int q = 0; q < 64; ++q) {
        int k = s * 64 + q;
        c += (W[(size_t)k * NN + col] != 0.0f) ? 1 : 0;
    }
    cnt16[col * 16 + s] = c;
}

// fused: scan (offs, off16) + rank (count-sort)
__global__ __launch_bounds__(1024) void k_scanrank(const int* __restrict__ cnt16,
        int* __restrict__ offs, int* __restrict__ off16,
        int* __restrict__ perm, int* __restrict__ iperm) {
    __shared__ int s[NN];
    int n = threadIdx.x;
    int t = 0;
#pragma unroll
    for (int q = 0; q < 16; ++q) t += cnt16[n * 16 + q];
    s[n] = t;
    __syncthreads();
    for (int d = 1; d < NN; d <<= 1) {
        int v = (n >= d) ? s[n - d] : 0;
        __syncthreads();
        s[n] += v;
        __syncthreads();
    }
    int incl = s[n];
    offs[n + 1] = (incl < MAXNNZ) ? incl : MAXNNZ;
    if (n == 0) offs[0] = 0;
    int base = incl - t;
#pragma unroll
    for (int q = 0; q < 16; ++q) {
        off16[n * 16 + q] = base;
        base += cnt16[n * 16 + q];
    }
    __syncthreads();
    int myc = t;
    s[n] = myc;
    __syncthreads();
    int r = 0;
    for (int m = 0; m < NN; ++m) {
        int cm = s[m];
        r += (cm > myc || (cm == myc && m < n)) ? 1 : 0;
    }
    perm[r] = n;
    iperm[n] = r;
}

__global__ __launch_bounds__(64) void k_fill16(const float* __restrict__ W, const int* __restrict__ off16,
                                               unsigned short* __restrict__ idx, float* __restrict__ val) {
    int bc = blockIdx.x;
    int s = bc & 15, g = bc >> 4;
    int col = g * 64 + threadIdx.x;
    int p = off16[col * 16 + s];
    for (int q = 0; q < 64; ++q) {
        int k = s * 64 + q;
        float w = W[(size_t)k * NN + col];
        if (w != 0.0f) { idx[p] = (unsigned short)k; val[p] = w; ++p; }
    }
}

// merged: block 0 = cohort-aware 2-choice table; blocks 1..16 = permwin
__global__ __launch_bounds__(1024) void k_choicepermwin(const int* __restrict__ offs,
        const unsigned short* __restrict__ gidx, const int* __restrict__ perm,
        const int* __restrict__ iperm, unsigned short* __restrict__ eidx2,
        const float* __restrict__ Win, float* __restrict__ Winp) {
    int n = threadIdx.x;
    if (blockIdx.x > 0) {
        // permwin: 65536 elems over 16 blocks x 1024 threads x 4
        int base = (blockIdx.x - 1) * 4096;
#pragma unroll
        for (int q = 0; q < 4; ++q) {
            int idx = base + q * 1024 + n;
            int i = idx >> 10, r = idx & 1023;
            Winp[idx] = Win[(i << 10) + perm[r]];
        }
        return;
    }
    __shared__ unsigned short rk[NN][NE];
    __shared__ unsigned short scnt[NN];
    __shared__ unsigned char ctr8[896][32];
    {
        int rr = n;
        int c = perm[rr];
        int o0 = offs[c];
        int cn = offs[c + 1] - o0;
        if (cn > NE) cn = NE;
        scnt[rr] = (unsigned short)cn;
        for (int j = 0; j < cn; ++j) rk[rr][j] = (unsigned short)iperm[(int)gidx[o0 + j]];
    }
    __syncthreads();
    int tid = n;
    if (tid < 896) {
        int task = tid >> 1, h = tid & 1;
        int w = task / NE, j = task % NE;
        unsigned char* mc = &ctr8[tid][0];
        for (int b = 0; b < 32; ++b) mc[b] = 0;
        unsigned sel = 0u;
        for (int l = 0; l < 32; ++l) {
            int rr = 64 * w + 32 * h + l;
            if (j < (int)scnt[rr]) {
                int rv = (int)rk[rr][j];
                int bA = rv & 31, bB = (rv ^ (rv >> 5)) & 31;
                if (mc[bA] <= mc[bB]) mc[bA]++;
                else { sel |= (1u << l); mc[bB]++; }
            }
        }
        for (int sweep = 0; sweep < 12; ++sweep) {
            bool ch = false;
            for (int l = 0; l < 32; ++l) {
                int rr = 64 * w + 32 * h + l;
                if (j < (int)scnt[rr]) {
                    int rv = (int)rk[rr][j];
                    int bA = rv & 31, bB = (rv ^ (rv >> 5)) & 31;
                    int isB = (int)((sel >> l) & 1u);
                    int cur = isB ? bB : bA, alt = isB ? bA : bB;
                    if ((int)mc[cur] > (int)mc[alt] + 1) {
                        mc[cur]--; mc[alt]++;
                        sel ^= (1u << l);
                        ch = true;
                    }
                }
            }
            if (!ch) break;
        }
        for (int l = 0; l < 32; ++l) {
            int rr = 64 * w + 32 * h + l;
            if (j < (int)scnt[rr]) {
                int rv = (int)rk[rr][j];
                int bB = (rv ^ (rv >> 5)) & 31;
                int addr = ((sel >> l) & 1u) ? (4096 + (((rv & ~31) | bB) << 2))
                                             : (rv << 2);
                eidx2[j * NN + rr] = (unsigned short)addr;
            }
        }
        int minb = 0, minl = (int)mc[0];
        for (int b = 1; b < 32; ++b)
            if ((int)mc[b] < minl) { minl = (int)mc[b]; minb = b; }
        unsigned short pad = (unsigned short)(minb << 2);
        for (int l = 0; l < 32; ++l) {
            int rr = 64 * w + 32 * h + l;
            if (j >= (int)scnt[rr]) eidx2[j * NN + rr] = pad;
        }
    }
}

// ---------- standalone input projection (prime chunk): U[t][b][r] fp16 ----------
__global__ __launch_bounds__(256) void k_uproj3(const float* __restrict__ In, const float* __restrict__ Winp,
                                                __half* __restrict__ U, int t0c, int nblk) {
    int b  = blockIdx.x / nblk;
    int tq = blockIdx.x % nblk;
    int t0 = t0c + tq * 32;
    __shared__ float s[32][NI + 1];
    int tid = threadIdx.x;
    {
        int i = tid >> 2, g = tid & 3;
        const float* ip = In + ((size_t)b * NI + i) * TT + t0 + g * 8;
        float4 v0 = *(const float4*)(ip);
        float4 v1 = *(const float4*)(ip + 4);
        s[g * 8 + 0][i] = v0.x; s[g * 8 + 1][i] = v0.y;
        s[g * 8 + 2][i] = v0.z; s[g * 8 + 3][i] = v0.w;
        s[g * 8 + 4][i] = v1.x; s[g * 8 + 5][i] = v1.y;
        s[g * 8 + 6][i] = v1.z; s[g * 8 + 7][i] = v1.w;
    }
    __syncthreads();
    const float4* W4 = (const float4*)Winp;
    uint2* U2 = (uint2*)U;
    for (int th = 0; th < 2; ++th) {
        float4 acc[16];
#pragma unroll
        for (int t = 0; t < 16; ++t) acc[t] = make_float4(0.f, 0.f, 0.f, 0.f);
        for (int i = 0; i < NI; ++i) {
            float4 w = W4[(size_t)i * 256 + tid];
#pragma unroll
            for (int t = 0; t < 16; ++t) {
                float sv = s[th * 16 + t][i];
                acc[t].x = fmaf(w.x, sv, acc[t].x);
                acc[t].y = fmaf(w.y, sv, acc[t].y);
                acc[t].z = fmaf(w.z, sv, acc[t].z);
                acc[t].w = fmaf(w.w, sv, acc[t].w);
            }
        }
#pragma unroll
        for (int t = 0; t < 16; ++t) {
            __half2 h01 = __floats2half2_rn(acc[t].x, acc[t].y);
            __half2 h23 = __floats2half2_rn(acc[t].z, acc[t].w);
            uint2 pk;
            pk.x = *(unsigned int*)&h01;
            pk.y = *(unsigned int*)&h23;
            U2[((size_t)(tq * 32 + th * 16 + t) * BB + b) * 256 + tid] = pk;
        }
    }
}

// ---------- recurrence helpers ----------
__device__ __forceinline__ float fast_tanh(float z) {
    float a = fabsf(z) * 2.885390082f;       // 2*log2(e)
    a = fminf(a, 60.0f);
    float e = __builtin_amdgcn_exp2f(a);     // e^{2|z|}
    float r = 1.0f - __fdividef(2.0f, e + 1.0f);
    return z < 0.0f ? -r : r;
}

#define L28(M) \
  M(0) M(1) M(2) M(3) M(4) M(5) M(6) M(7) M(8) M(9) M(10) M(11) M(12) M(13) \
  M(14) M(15) M(16) M(17) M(18) M(19) M(20) M(21) M(22) M(23) M(24) M(25) M(26) M(27)

#define DW(i)  float w##i; int a##i;
#define IW(i)  { a##i = (int)eidx2[(i) * NN + n]; \
                 w##i = (cnt > i) ? gval[o0 + i] : 0.0f; }

#define PIN_ALL \
  asm volatile("" : "+v"(w0),"+v"(w1),"+v"(w2),"+v"(w3),"+v"(w4),"+v"(w5),"+v"(w6),"+v"(w7)); \
  asm volatile("" : "+v"(w8),"+v"(w9),"+v"(w10),"+v"(w11),"+v"(w12),"+v"(w13),"+v"(w14),"+v"(w15)); \
  asm volatile("" : "+v"(w16),"+v"(w17),"+v"(w18),"+v"(w19),"+v"(w20),"+v"(w21),"+v"(w22),"+v"(w23)); \
  asm volatile("" : "+v"(w24),"+v"(w25),"+v"(w26),"+v"(w27)); \
  asm volatile("" : "+v"(a0),"+v"(a1),"+v"(a2),"+v"(a3),"+v"(a4),"+v"(a5),"+v"(a6),"+v"(a7)); \
  asm volatile("" : "+v"(a8),"+v"(a9),"+v"(a10),"+v"(a11),"+v"(a12),"+v"(a13),"+v"(a14),"+v"(a15)); \
  asm volatile("" : "+v"(a16),"+v"(a17),"+v"(a18),"+v"(a19),"+v"(a20),"+v"(a21),"+v"(a22),"+v"(a23)); \
  asm volatile("" : "+v"(a24),"+v"(a25),"+v"(a26),"+v"(a27));

#define GRP(J, i0, i1, i2, i3) \
  if ((J) < wmax) { \
    float q0 = *(const float*)(xp + a##i0); \
    float q1 = *(const float*)(xp + a##i1); \
    float q2 = *(const float*)(xp + a##i2); \
    float q3 = *(const float*)(xp + a##i3); \
    z0 = fmaf(w##i0, q0, z0); z1 = fmaf(w##i1, q1, z1); \
    z2 = fmaf(w##i2, q2, z2); z3 = fmaf(w##i3, q3, z3); \
  }

#define GATHER_ALL \
  GRP(0, 0,1,2,3)      GRP(4, 4,5,6,7)      GRP(8, 8,9,10,11) \
  GRP(12, 12,13,14,15) GRP(16, 16,17,18,19) GRP(20, 20,21,22,23) \
  GRP(24, 24,25,26,27)

// prefetch depth 2 with clamp tlim (inclusive max t)
#define STEPX(PH, XDST) { \
    float u = un1; un1 = un2; \
    int tn = t + 2; tn = (tn < tlim) ? tn : tlim; \
    un2 = (float)Ub[(size_t)tn * ustep]; \
    const char* xp = xb + (PH); \
    float z0 = u, z1 = 0.f, z2 = 0.f, z3 = 0.f; \
    GATHER_ALL \
    x = 0.5f * x + 0.5f * fast_tanh((z0 + z1) + (z2 + z3)); \
    XDST = x; \
    float* wb = (float*)(xb + ((PH) ^ 8192)); \
    wb[n] = x; \
    wb[NN + nB] = x; \
    __syncthreads(); \
    ++t; \
}

#define REC16 \
    PIN_ALL \
    int t = tb; \
    float y0, y1, y2, y3, y4, y5, y6, y7, y8, y9, y10, y11, y12, y13, y14, y15; \
    STEPX(0,    y0)  STEPX(8192, y1)  STEPX(0,    y2)  STEPX(8192, y3) \
    STEPX(0,    y4)  STEPX(8192, y5)  STEPX(0,    y6)  STEPX(8192, y7) \
    STEPX(0,    y8)  STEPX(8192, y9)  STEPX(0,    y10) STEPX(8192, y11) \
    STEPX(0,    y12) STEPX(8192, y13) STEPX(0,    y14) STEPX(8192, y15)

// ---------- fused: blocks 0..127 recurrence [t0r,t0r+Tc); 128..255 uproj [t0u,t0u+Tcu) ----------
__global__ __launch_bounds__(1024, 4)
void k_fused(const __half* __restrict__ Uread, __half* __restrict__ Uwrite,
             const float* __restrict__ In, const float* __restrict__ Winp,
             const int* __restrict__ offs, const unsigned short* __restrict__ eidx2,
             const float* __restrict__ gval, const int* __restrict__ perm,
             float* __restrict__ out, float* __restrict__ xstate,
             int t0r, int Tc, int t0u, int Tcu) {
    __shared__ float smem[4 * 32 * 65];      // 33280 B; recurrence uses first 16 KB
    int tid = threadIdx.x;
    if (blockIdx.x < BB) {
        int b = blockIdx.x, n = tid;
        int c = perm[n];
        int nB = (n & ~31) | ((n ^ (n >> 5)) & 31);
        int o0 = offs[c];
        int cnt = offs[c + 1] - o0;
        L28(DW)
        L28(IW)
        PIN_ALL
        int wmax = cnt;
#pragma unroll
        for (int d = 1; d < 64; d <<= 1) {
            int o = __shfl_xor(wmax, d);
            wmax = wmax > o ? wmax : o;
        }
        wmax = __builtin_amdgcn_readfirstlane(wmax);

        float x = (t0r == 0) ? 0.0f : xstate[((size_t)b << 10) + n];
        smem[n] = x;
        smem[NN + nB] = x;
        __syncthreads();

        char* xb = (char*)&smem[0];
        const __half* Ub = Uread + (size_t)b * NN + n;
        const size_t ustep = (size_t)BB * NN;
        int tlim = Tc - 1;
        float un1 = (float)Ub[0];
        float un2 = (float)Ub[(size_t)((1 < Tc) ? 1 : 0) * ustep];

        for (int tb = 0; tb < Tc; tb += TH) {
            REC16
            float4* op = (float4*)(out + ((size_t)b * NN + c) * TT + (size_t)(t0r + tb));
            op[0] = make_float4(y0,  y1,  y2,  y3);
            op[1] = make_float4(y4,  y5,  y6,  y7);
            op[2] = make_float4(y8,  y9,  y10, y11);
            op[3] = make_float4(y12, y13, y14, y15);
        }
        if (t0r + Tc < TT) xstate[((size_t)b << 10) + n] = x;
    } else {
        if (Tcu <= 0) return;
        int b = blockIdx.x - BB;
        int sub = tid >> 8, stid = tid & 255;
        float* sg = smem + sub * 32 * 65;     // [t][i] view: sg[t*65+i]
        const float4* W4 = (const float4*)Winp;
        uint2* U2w = (uint2*)Uwrite;
        int ntile = Tcu >> 5;
        int nrep = (ntile + 3) >> 2;
        for (int rep = 0; rep < nrep; ++rep) {
            int tq = rep * 4 + sub;
            bool act = tq < ntile;
            int tg = t0u + tq * 32;
            __syncthreads();
            if (act) {
                int i = stid >> 2, g4 = stid & 3;
                const float* ip = In + ((size_t)b * NI + i) * TT + tg + g4 * 8;
                float4 v0 = *(const float4*)(ip);
                float4 v1 = *(const float4*)(ip + 4);
                sg[(g4 * 8 + 0) * 65 + i] = v0.x; sg[(g4 * 8 + 1) * 65 + i] = v0.y;
                sg[(g4 * 8 + 2) * 65 + i] = v0.z; sg[(g4 * 8 + 3) * 65 + i] = v0.w;
                sg[(g4 * 8 + 4) * 65 + i] = v1.x; sg[(g4 * 8 + 5) * 65 + i] = v1.y;
                sg[(g4 * 8 + 6) * 65 + i] = v1.z; sg[(g4 * 8 + 7) * 65 + i] = v1.w;
            }
            __syncthreads();
            if (act) {
                for (int th = 0; th < 2; ++th) {
                    float4 acc[16];
#pragma unroll
                    for (int t = 0; t < 16; ++t) acc[t] = make_float4(0.f, 0.f, 0.f, 0.f);
                    for (int i = 0; i < NI; ++i) {
                        float4 w = W4[(size_t)i * 256 + stid];
#pragma unroll
                        for (int t = 0; t < 16; ++t) {
                            float sv = sg[(th * 16 + t) * 65 + i];
                            acc[t].x = fmaf(w.x, sv, acc[t].x);
                            acc[t].y = fmaf(w.y, sv, acc[t].y);
                            acc[t].z = fmaf(w.z, sv, acc[t].z);
                            acc[t].w = fmaf(w.w, sv, acc[t].w);
                        }
                    }
#pragma unroll
                    for (int t = 0; t < 16; ++t) {
                        __half2 h01 = __floats2half2_rn(acc[t].x, acc[t].y);
                        __half2 h23 = __floats2half2_rn(acc[t].z, acc[t].w);
                        uint2 pk;
                        pk.x = *(unsigned int*)&h01;
                        pk.y = *(unsigned int*)&h23;
                        U2w[((size_t)(tq * 32 + th * 16 + t) * BB + b) * 256 + stid] = pk;
                    }
                }
            }
        }
    }
}

extern "C" void kernel_launch(void* const* d_in, const int* in_sizes, int n_in,
                              void* d_out, int out_size, void* d_ws, size_t ws_size,
                              hipStream_t stream) {
    const float* In  = (const float*)d_in[0];
    const float* W   = (const float*)d_in[1];
    const float* Win = (const float*)d_in[2];
    float* out = (float*)d_out;
    char* ws = (char*)d_ws;
    int* offs           = (int*)(ws + WS_OFFS);
    unsigned short* idx = (unsigned short*)(ws + WS_IDX);
    float* val          = (float*)(ws + WS_VAL);
    int* perm           = (int*)(ws + WS_PERM);
    int* iperm          = (int*)(ws + WS_IPERM);
    float* xstate       = (float*)(ws + WS_XSTATE);
    float* Winp         = (float*)(ws + WS_WINP);
    unsigned short* eidx2 = (unsigned short*)(ws + WS_EIDX2);
    int* cnt16          = (int*)(ws + WS_CNT16);
    int* off16          = (int*)(ws + WS_OFF16);
    __half* U0          = (__half*)(ws + WS_U);
    __half* U1          = (__half*)(ws + WS_U2);

    k_count16<<<256, 64, 0, stream>>>(W, cnt16);
    k_scanrank<<<1, 1024, 0, stream>>>(cnt16, offs, off16, perm, iperm);
    k_fill16<<<256, 64, 0, stream>>>(W, off16, idx, val);
    k_choicepermwin<<<17, 1024, 0, stream>>>(offs, idx, perm, iperm, eidx2, Win, Winp);

    if ((size_t)WS_U2 + (size_t)256 * BB * NN * 2 <= ws_size) {
        // balanced stagger: prime 64 (full GPU), then rec c_i || up c_{i+1}
        // chunks: 64 / 96 / 160 / 192
        k_uproj3<<<BB * 2, 256, 0, stream>>>(In, Winp, U0, 0, 2);
        k_fused<<<2 * BB, 1024, 0, stream>>>(U0, U1, In, Winp, offs, eidx2, val, perm,
                                             out, xstate, 0, 64, 64, 96);
        k_fused<<<2 * BB, 1024, 0, stream>>>(U1, U0, In, Winp, offs, eidx2, val, perm,
                                             out, xstate, 64, 96, 160, 160);
        k_fused<<<2 * BB, 1024, 0, stream>>>(U0, U1, In, Winp, offs, eidx2, val, perm,
                                             out, xstate, 160, 160, 320, 192);
        k_fused<<<BB, 1024, 0, stream>>>(U1, U0, In, Winp, offs, eidx2, val, perm,
                                         out, xstate, 320, 192, TT, 0);
    } else {
        // fallback: serial chunks of 128 in U0
        for (int t0 = 0; t0 < TT; t0 += 128) {
            k_uproj3<<<BB * 4, 256, 0, stream>>>(In, Winp, U0, t0, 4);
            k_fused<<<BB, 1024, 0, stream>>>(U0, U0, In, Winp, offs, eidx2, val, perm,
                                             out, xstate, t0, 128, TT, 0);
        }
    }
}